// Round 13
// baseline (99.469 us; speedup 1.0000x reference)
//
#include <hip/hip_runtime.h>
#include <stdint.h>
#include <stddef.h>

#define NS 8192
#define NT 8192
#define DD 512
#define NSEC 6
#define QS 32.0f                                 // quant scale: q = rint(32*x)
#define INV_S2 (1.0f / (QS * QS))                // 1/1024
#define INV_DNT (1.0f / ((float)DD * (float)NT))
#define INV_NT  (1.0f / (float)NT)

typedef __attribute__((ext_vector_type(4))) int i32x4;
typedef __attribute__((ext_vector_type(16))) int i32x16;

// ---- workspace layout (bytes) ----
#define WS_A    ((size_t)0)                  // NS*DD i8
#define WS_B    (WS_A + (size_t)NS * DD)     // NT*DD i8
#define WS_SQS  (WS_B + (size_t)NT * DD)     // NS f32 raw row sumsq (exact fp32)
#define WS_SQT  (WS_SQS + (size_t)NS * 4)    // NT f32
#define WS_TS   (WS_SQT + (size_t)NT * 4)    // NSEC*DD i32 per-section q col-sums
#define WS_CNT  (WS_TS + (size_t)NSEC * DD * 4)  // NSEC f32
#define WS_SSQ  (WS_CNT + NSEC * 4)              // NSEC f32
#define WS_ZEND (WS_SSQ + NSEC * 4)

__device__ __forceinline__ void gload16(const void* g, void* l) {
  __builtin_amdgcn_global_load_lds(
      (const __attribute__((address_space(1))) unsigned int*)g,
      (__attribute__((address_space(3))) unsigned int*)l, 16, 0, 0);
}

// ============================================================================
// prep: fp32 -> i8 RTN quantization (scale 32) + exact fp32 row sum-of-squares.
// Block 0 zeroes the TS/CNT/SSQ accumulator region (replaces hipMemsetAsync).
// ============================================================================
__global__ __launch_bounds__(256) void prep_kernel(
    const float* __restrict__ src, const float* __restrict__ tgt,
    char* __restrict__ ws) {
  const int tid = threadIdx.x, wid = tid >> 6, lane = tid & 63;
  char* Ai8 = ws + WS_A;
  char* Bi8 = ws + WS_B;
  float* sqs = (float*)(ws + WS_SQS);
  float* sqt = (float*)(ws + WS_SQT);

  if (blockIdx.x == 0) {                     // zero TS/CNT/SSQ (3084 dwords)
    int* Z = (int*)(ws + WS_TS);
    for (int i = tid; i < (int)((WS_ZEND - WS_TS) >> 2); i += 256) Z[i] = 0;
  }

#pragma unroll
  for (int it = 0; it < 4; ++it) {
    const int row = blockIdx.x * 4 + wid + it * 4096;   // 0..16383
    const bool isT = row >= NS;
    const int r = isT ? row - NS : row;
    const float* in = (isT ? tgt : src) + (size_t)r * DD;
    const float4* rp = (const float4*)in;
    float4 v0 = rp[lane * 2], v1 = rp[lane * 2 + 1];
    float x[8] = {v0.x, v0.y, v0.z, v0.w, v1.x, v1.y, v1.z, v1.w};
    float ss = 0.f;
    int q[8];
#pragma unroll
    for (int j = 0; j < 8; ++j) {
      ss += x[j] * x[j];
      int qi = __float2int_rn(x[j] * QS);           // RTN, unbiased
      q[j] = min(127, max(-127, qi));
    }
    const int lo = (q[0] & 255) | ((q[1] & 255) << 8) |
                   ((q[2] & 255) << 16) | ((q[3] & 255) << 24);
    const int hi = (q[4] & 255) | ((q[5] & 255) << 8) |
                   ((q[6] & 255) << 16) | ((q[7] & 255) << 24);
    *(int2*)((isT ? Bi8 : Ai8) + (size_t)r * DD + lane * 8) = make_int2(lo, hi);
#pragma unroll
    for (int off = 32; off >= 1; off >>= 1) ss += __shfl_xor(ss, off, 64);
    if (lane == 0) (isT ? sqt : sqs)[r] = ss;
  }
}

// ============================================================================
// tsumq: per-section INTEGER column sums T[6][512] of the quantized targets,
// plus per-section cnt / sum(sqt).  256 blocks x 512 thr, 32 rows/block.
// Also zeroes the loss_c half of out (first 8192 global threads) -- this
// replaces the standalone ls_kernel's zeroing and orders before gram.
// ============================================================================
__global__ __launch_bounds__(512) void tsumq_kernel(
    const int* __restrict__ tsec, char* __restrict__ ws,
    float* __restrict__ out) {
  const int gid = blockIdx.x * 512 + threadIdx.x;
  if (gid < NS) out[NS + gid] = 0.f;            // loss_c accumulator base

  const int d = threadIdx.x;
  const int r0 = blockIdx.x * 32;
  const signed char* B = (const signed char*)(ws + WS_B);
  int a[NSEC] = {0, 0, 0, 0, 0, 0};
#pragma unroll 4
  for (int r = 0; r < 32; ++r) {
    const int sec = tsec[r0 + r];
    const int v = (int)B[(size_t)(r0 + r) * DD + d];
#pragma unroll
    for (int c = 0; c < NSEC; ++c) a[c] += (sec == c) ? v : 0;
  }
  int* T = (int*)(ws + WS_TS);
#pragma unroll
  for (int c = 0; c < NSEC; ++c) atomicAdd(&T[c * DD + d], a[c]);

  if (threadIdx.x < 32) {                       // cnt / ssq via half-wave 0
    const float* sqt = (const float*)(ws + WS_SQT);
    const int r = r0 + threadIdx.x;
    const int sec = tsec[r];
    const float qv = sqt[r];
    float cn[NSEC], sq[NSEC];
#pragma unroll
    for (int c = 0; c < NSEC; ++c) {
      cn[c] = (sec == c) ? 1.f : 0.f;
      sq[c] = (sec == c) ? qv : 0.f;
    }
#pragma unroll
    for (int c = 0; c < NSEC; ++c) {
#pragma unroll
      for (int off = 16; off >= 1; off >>= 1) {
        cn[c] += __shfl_xor(cn[c], off, 64);
        sq[c] += __shfl_xor(sq[c], off, 64);
      }
    }
    if (threadIdx.x == 0) {
      float* cnt = (float*)(ws + WS_CNT);
      float* ssq = (float*)(ws + WS_SSQ);
#pragma unroll
      for (int c = 0; c < NSEC; ++c) {
        atomicAdd(&cnt[c], cn[c]);
        atomicAdd(&ssq[c], sq[c]);
      }
    }
  }
}

// ============================================================================
// gram (i8): block 128x256, BK=64, 4 waves (2M x 2N), per-wave 64x128 =
// 2x4 frags of mfma_i32_32x32x32_i8.  3-buffer LDS pipeline, counted
// vmcnt(6).  Epilogue = hinge DETECTION only; cold path recomputes exactly.
// NEW: the 64 blocks with n_blk==0 (covering all m-panels bijectively)
// compute loss_s for their 128 rows FIRST via the exact integer identity
//   sum_{t same} g_int = q_s . T_c  ->  out[s] = (cnt*sqs + ssq - dot/512)/DNt
// -- replaces the standalone ls_kernel dispatch (runs concurrent with other
// blocks' gram work).
// ============================================================================
__global__ __launch_bounds__(256, 2) void gram_kernel(
    const char* __restrict__ ws, const int* __restrict__ ssec,
    const int* __restrict__ tsec, float* __restrict__ out) {
  __shared__ __align__(16) char lds[3][24576];   // [buf][A 8KB | B 16KB]

  const float* sqs = (const float*)(ws + WS_SQS);
  const float* sqt = (const float*)(ws + WS_SQT);

  const int lin = blockIdx.x;                  // 2048 = 64(m) x 32(n)
  const int xcd = lin & 7, ii = lin >> 3;
  const int m_blk = xcd * 8 + (ii & 7);
  const int n_blk = ii >> 3;
  const int rowA = m_blk * 128, rowB = n_blk * 256;

  const int tid = threadIdx.x, wid = tid >> 6, lane = tid & 63;
  const int wr = wid >> 1, wc = wid & 1;       // 2M x 2N wave grid
  const int lh = lane >> 5;

  // ---- ls-duty (n_blk == 0 blocks only): loss_s for rows rowA..rowA+127 ----
  if (n_blk == 0) {
    const signed char* A = (const signed char*)(ws + WS_A);
    const int* Tb = (const int*)(ws + WS_TS);
    const float* cnt = (const float*)(ws + WS_CNT);
    const float* ssq = (const float*)(ws + WS_SSQ);
    for (int rr = 0; rr < 32; ++rr) {
      const int row = rowA + wid * 32 + rr;
      const int c = ssec[row];
      const int* T = Tb + c * DD;
      union { int2 v; signed char b[8]; } u;
      u.v = *(const int2*)(A + (size_t)row * DD + lane * 8);
      i32x4 t0 = *(const i32x4*)(T + lane * 8);
      i32x4 t1 = *(const i32x4*)(T + lane * 8 + 4);
      int s = (int)u.b[0] * t0[0] + (int)u.b[1] * t0[1] +
              (int)u.b[2] * t0[2] + (int)u.b[3] * t0[3] +
              (int)u.b[4] * t1[0] + (int)u.b[5] * t1[1] +
              (int)u.b[6] * t1[2] + (int)u.b[7] * t1[3];
#pragma unroll
      for (int off = 32; off >= 1; off >>= 1) s += __shfl_xor(s, off, 64);
      if (lane == 0)
        out[row] = (cnt[c] * sqs[row] + ssq[c] - (float)s * (1.0f / 512.0f)) *
                   INV_DNT;
    }
  }

  // ---- staging: A 2 chunks, B 4 chunks per thread (16B each) ----
  const char* aSrc[2];
  const char* bSrc[4];
  int aDst[2], bDst[4];
#pragma unroll
  for (int ih = 0; ih < 2; ++ih) {
    const int o = ih * 4096 + tid * 16;
    const int row_p = o >> 6;
    const int bl = (o & 63) ^ (((row_p >> 1) & 3) << 4);
    aDst[ih] = ih * 4096 + wid * 1024;
    aSrc[ih] = ws + WS_A + (size_t)(rowA + row_p) * DD + bl;
  }
#pragma unroll
  for (int ih = 0; ih < 4; ++ih) {
    const int o = ih * 4096 + tid * 16;
    const int row_p = o >> 6;
    const int bl = (o & 63) ^ (((row_p >> 1) & 3) << 4);
    bDst[ih] = 8192 + ih * 4096 + wid * 1024;
    bSrc[ih] = ws + WS_B + (size_t)(rowB + row_p) * DD + bl;
  }

#define STAGE(T, BUF)                                             \
  {                                                               \
    gload16(aSrc[0] + (size_t)(T) * 64, &lds[BUF][aDst[0]]);      \
    gload16(aSrc[1] + (size_t)(T) * 64, &lds[BUF][aDst[1]]);      \
    gload16(bSrc[0] + (size_t)(T) * 64, &lds[BUF][bDst[0]]);      \
    gload16(bSrc[1] + (size_t)(T) * 64, &lds[BUF][bDst[1]]);      \
    gload16(bSrc[2] + (size_t)(T) * 64, &lds[BUF][bDst[2]]);      \
    gload16(bSrc[3] + (size_t)(T) * 64, &lds[BUF][bDst[3]]);      \
  }

  // ---- fragment read offsets (phys = logical ^ (((row>>1)&3)<<4)) ----
  int aOff[2][2], bOff[4][2];
#pragma unroll
  for (int kk = 0; kk < 2; ++kk) {
    const int l = kk * 32 + lh * 16;
#pragma unroll
    for (int mi = 0; mi < 2; ++mi) {
      const int ra = wr * 64 + mi * 32 + (lane & 31);
      aOff[mi][kk] = ra * 64 + (l ^ (((ra >> 1) & 3) << 4));
    }
#pragma unroll
    for (int ni = 0; ni < 4; ++ni) {
      const int rb = wc * 128 + ni * 32 + (lane & 31);
      bOff[ni][kk] = 8192 + rb * 64 + (l ^ (((rb >> 1) & 3) << 4));
    }
  }

  i32x16 acc[2][4];
#pragma unroll
  for (int mi = 0; mi < 2; ++mi)
#pragma unroll
    for (int ni = 0; ni < 4; ++ni)
#pragma unroll
      for (int j = 0; j < 16; ++j) acc[mi][ni][j] = 0;

  // ---- prologue ----
  STAGE(0, 0)
  STAGE(1, 1)
  asm volatile("s_waitcnt vmcnt(6)" ::: "memory");
  __builtin_amdgcn_sched_barrier(0);
  __builtin_amdgcn_s_barrier();

#pragma unroll
  for (int t = 0; t < 8; ++t) {
    const int cur = t % 3;
    if (t + 2 < 8) STAGE(t + 2, (t + 2) % 3)

    i32x4 a[2][2], b[4][2];
#pragma unroll
    for (int kk = 0; kk < 2; ++kk) {
#pragma unroll
      for (int mi = 0; mi < 2; ++mi)
        a[mi][kk] = *(const i32x4*)&lds[cur][aOff[mi][kk]];
#pragma unroll
      for (int ni = 0; ni < 4; ++ni)
        b[ni][kk] = *(const i32x4*)&lds[cur][bOff[ni][kk]];
    }
#pragma unroll
    for (int kk = 0; kk < 2; ++kk)
#pragma unroll
      for (int mi = 0; mi < 2; ++mi)
#pragma unroll
        for (int ni = 0; ni < 4; ++ni)
          acc[mi][ni] = __builtin_amdgcn_mfma_i32_32x32x32_i8(
              a[mi][kk], b[ni][kk], acc[mi][ni], 0, 0, 0);

    __builtin_amdgcn_sched_barrier(0);
    if (t + 2 < 8) {
      asm volatile("s_waitcnt vmcnt(6)" ::: "memory");   // tile t+1 landed
    } else if (t == 6) {
      asm volatile("s_waitcnt vmcnt(0)" ::: "memory");   // tile 7 landed
    }
    __builtin_amdgcn_sched_barrier(0);
    if (t < 7) __builtin_amdgcn_s_barrier();
  }
#undef STAGE

  // ---- epilogue: hinge detection only ----
  const int colc = lane & 31;
  float sqc[4];
#pragma unroll
  for (int ni = 0; ni < 4; ++ni)
    sqc[ni] = sqt[rowB + wc * 128 + ni * 32 + colc];

  float smin = sqs[rowA + wr * 64 + lane];       // wave-min of its 64 rows
#pragma unroll
  for (int off = 32; off >= 1; off >>= 1)
    smin = fminf(smin, __shfl_xor(smin, off, 64));

  int thr[4];
#pragma unroll
  for (int ni = 0; ni < 4; ++ni)
    thr[ni] = (int)((smin + sqc[ni] - 129.0f) * 512.0f);

  int mx[4] = {(int)0x80000000, (int)0x80000000,
               (int)0x80000000, (int)0x80000000};
#pragma unroll
  for (int mi = 0; mi < 2; ++mi)
#pragma unroll
    for (int ni = 0; ni < 4; ++ni)
#pragma unroll
      for (int j = 0; j < 16; ++j) mx[ni] = max(mx[ni], acc[mi][ni][j]);

  const bool fire = (mx[0] > thr[0]) || (mx[1] > thr[1]) ||
                    (mx[2] > thr[2]) || (mx[3] > thr[3]);
  if (__any(fire)) {                              // cold path (~never)
#pragma unroll
    for (int mi = 0; mi < 2; ++mi) {
#pragma unroll
      for (int j = 0; j < 16; ++j) {
        const int rowin = (j & 3) + 8 * (j >> 2) + 4 * lh;
        const int grow = rowA + wr * 64 + mi * 32 + rowin;
        const float sqr = sqs[grow];
        const int sc = ssec[grow];
#pragma unroll
        for (int ni = 0; ni < 4; ++ni) {
          const int gcol = rowB + wc * 128 + ni * 32 + colc;
          const float d2r =
              sqr + sqc[ni] - 2.f * (float)acc[mi][ni][j] * INV_S2;
          if (d2r < 128.f) {
            if (sc != tsec[gcol]) {                 // hinge contribution
              const float d = sqrtf(fmaxf(d2r, 0.f) * (1.f / (float)DD));
              const float hh = 0.5f - d;
              atomicAdd(&out[NS + grow], hh * hh * INV_NT);
            } else if (d2r < 0.f) {                 // clamp fix for loss_s
              atomicAdd(&out[grow], -d2r * INV_DNT);
            }
          }
        }
      }
    }
  }
}

extern "C" void kernel_launch(void* const* d_in, const int* in_sizes, int n_in,
                              void* d_out, int out_size, void* d_ws, size_t ws_size,
                              hipStream_t stream) {
  const float* src = (const float*)d_in[0];
  const float* tgt = (const float*)d_in[1];
  const int* ssec = (const int*)d_in[2];
  const int* tsec = (const int*)d_in[3];
  float* out = (float*)d_out;
  char* ws = (char*)d_ws;

  prep_kernel<<<1024, 256, 0, stream>>>(src, tgt, ws);
  tsumq_kernel<<<256, 512, 0, stream>>>(tsec, ws, out);
  gram_kernel<<<2048, 256, 0, stream>>>(ws, ssec, tsec, out);
}

// Round 14
// 82.011 us; speedup vs baseline: 1.2129x; 1.2129x over previous
//
#include <hip/hip_runtime.h>
#include <stdint.h>
#include <stddef.h>

#define NS 8192
#define NT 8192
#define DD 512
#define NSEC 6
#define QS 32.0f                                 // quant scale: q = rint(32*x)
#define INV_S2 (1.0f / (QS * QS))                // 1/1024
#define INV_DNT (1.0f / ((float)DD * (float)NT))
#define INV_NT  (1.0f / (float)NT)

typedef __attribute__((ext_vector_type(4))) int i32x4;
typedef __attribute__((ext_vector_type(16))) int i32x16;

// ---- workspace layout (bytes) ----
#define WS_A    ((size_t)0)                  // NS*DD i8
#define WS_B    (WS_A + (size_t)NS * DD)     // NT*DD i8
#define WS_SQS  (WS_B + (size_t)NT * DD)     // NS f32 raw row sumsq (exact fp32)
#define WS_SQT  (WS_SQS + (size_t)NS * 4)    // NT f32
#define WS_TS   (WS_SQT + (size_t)NT * 4)    // NSEC*DD i32 per-section q col-sums
#define WS_CNT  (WS_TS + (size_t)NSEC * DD * 4)  // NSEC f32
#define WS_SSQ  (WS_CNT + NSEC * 4)              // NSEC f32
#define WS_ZEND (WS_SSQ + NSEC * 4)

__device__ __forceinline__ void gload16(const void* g, void* l) {
  __builtin_amdgcn_global_load_lds(
      (const __attribute__((address_space(1))) unsigned int*)g,
      (__attribute__((address_space(3))) unsigned int*)l, 16, 0, 0);
}

// ============================================================================
// prep: fp32 -> i8 RTN quantization (scale 32) + exact fp32 row sum-of-squares.
// Block 0 zeroes the TS/CNT/SSQ accumulator region (replaces hipMemsetAsync).
// ============================================================================
__global__ __launch_bounds__(256) void prep_kernel(
    const float* __restrict__ src, const float* __restrict__ tgt,
    char* __restrict__ ws) {
  const int tid = threadIdx.x, wid = tid >> 6, lane = tid & 63;
  char* Ai8 = ws + WS_A;
  char* Bi8 = ws + WS_B;
  float* sqs = (float*)(ws + WS_SQS);
  float* sqt = (float*)(ws + WS_SQT);

  if (blockIdx.x == 0) {                     // zero TS/CNT/SSQ (3084 dwords)
    int* Z = (int*)(ws + WS_TS);
    for (int i = tid; i < (int)((WS_ZEND - WS_TS) >> 2); i += 256) Z[i] = 0;
  }

#pragma unroll
  for (int it = 0; it < 4; ++it) {
    const int row = blockIdx.x * 4 + wid + it * 4096;   // 0..16383
    const bool isT = row >= NS;
    const int r = isT ? row - NS : row;
    const float* in = (isT ? tgt : src) + (size_t)r * DD;
    const float4* rp = (const float4*)in;
    float4 v0 = rp[lane * 2], v1 = rp[lane * 2 + 1];
    float x[8] = {v0.x, v0.y, v0.z, v0.w, v1.x, v1.y, v1.z, v1.w};
    float ss = 0.f;
    int q[8];
#pragma unroll
    for (int j = 0; j < 8; ++j) {
      ss += x[j] * x[j];
      int qi = __float2int_rn(x[j] * QS);           // RTN, unbiased
      q[j] = min(127, max(-127, qi));
    }
    const int lo = (q[0] & 255) | ((q[1] & 255) << 8) |
                   ((q[2] & 255) << 16) | ((q[3] & 255) << 24);
    const int hi = (q[4] & 255) | ((q[5] & 255) << 8) |
                   ((q[6] & 255) << 16) | ((q[7] & 255) << 24);
    *(int2*)((isT ? Bi8 : Ai8) + (size_t)r * DD + lane * 8) = make_int2(lo, hi);
#pragma unroll
    for (int off = 32; off >= 1; off >>= 1) ss += __shfl_xor(ss, off, 64);
    if (lane == 0) (isT ? sqt : sqs)[r] = ss;
  }
}

// ============================================================================
// tsumq: per-section INTEGER column sums T[6][512] of the quantized targets,
// plus per-section cnt / sum(sqt).  128 blocks x 512 thr (thread = column),
// 64 rows/block -- the PROVEN fast shape (r12, ~4 us); 256x32 regressed to
// 47 us (atomic-count doubling -> cross-XCD L2 line ping-pong).
// Also zeroes the loss_c half of out (first 8192 of 65536 global threads).
// ============================================================================
__global__ __launch_bounds__(512) void tsumq_kernel(
    const int* __restrict__ tsec, char* __restrict__ ws,
    float* __restrict__ out) {
  const int gid = blockIdx.x * 512 + threadIdx.x;
  if (gid < NS) out[NS + gid] = 0.f;            // loss_c accumulator base

  const int d = threadIdx.x;
  const int r0 = blockIdx.x * 64;
  const signed char* B = (const signed char*)(ws + WS_B);
  int a[NSEC] = {0, 0, 0, 0, 0, 0};
#pragma unroll 4
  for (int r = 0; r < 64; ++r) {
    const int sec = tsec[r0 + r];
    const int v = (int)B[(size_t)(r0 + r) * DD + d];
#pragma unroll
    for (int c = 0; c < NSEC; ++c) a[c] += (sec == c) ? v : 0;
  }
  int* T = (int*)(ws + WS_TS);
#pragma unroll
  for (int c = 0; c < NSEC; ++c) atomicAdd(&T[c * DD + d], a[c]);

  if (threadIdx.x < 64) {                       // cnt / ssq via wave 0
    const float* sqt = (const float*)(ws + WS_SQT);
    const int r = r0 + threadIdx.x;
    const int sec = tsec[r];
    const float qv = sqt[r];
    float cn[NSEC], sq[NSEC];
#pragma unroll
    for (int c = 0; c < NSEC; ++c) {
      cn[c] = (sec == c) ? 1.f : 0.f;
      sq[c] = (sec == c) ? qv : 0.f;
    }
#pragma unroll
    for (int c = 0; c < NSEC; ++c) {
#pragma unroll
      for (int off = 32; off >= 1; off >>= 1) {
        cn[c] += __shfl_xor(cn[c], off, 64);
        sq[c] += __shfl_xor(sq[c], off, 64);
      }
    }
    if (threadIdx.x == 0) {
      float* cnt = (float*)(ws + WS_CNT);
      float* ssq = (float*)(ws + WS_SSQ);
#pragma unroll
      for (int c = 0; c < NSEC; ++c) {
        atomicAdd(&cnt[c], cn[c]);
        atomicAdd(&ssq[c], sq[c]);
      }
    }
  }
}

// ============================================================================
// gram (i8): block 128x256, BK=64, 4 waves (2M x 2N), per-wave 64x128 =
// 2x4 frags of mfma_i32_32x32x32_i8.  3-buffer LDS pipeline, counted
// vmcnt(6).  Epilogue = hinge DETECTION only; cold path recomputes exactly.
// The 64 blocks with n_blk==0 (covering all m-panels bijectively) compute
// loss_s for their 128 rows first via the exact integer identity
//   sum_{t same} g_int = q_s . T_c  ->  out[s] = (cnt*sqs + ssq - dot/512)/DNt
// ============================================================================
__global__ __launch_bounds__(256, 2) void gram_kernel(
    const char* __restrict__ ws, const int* __restrict__ ssec,
    const int* __restrict__ tsec, float* __restrict__ out) {
  __shared__ __align__(16) char lds[3][24576];   // [buf][A 8KB | B 16KB]

  const float* sqs = (const float*)(ws + WS_SQS);
  const float* sqt = (const float*)(ws + WS_SQT);

  const int lin = blockIdx.x;                  // 2048 = 64(m) x 32(n)
  const int xcd = lin & 7, ii = lin >> 3;
  const int m_blk = xcd * 8 + (ii & 7);
  const int n_blk = ii >> 3;
  const int rowA = m_blk * 128, rowB = n_blk * 256;

  const int tid = threadIdx.x, wid = tid >> 6, lane = tid & 63;
  const int wr = wid >> 1, wc = wid & 1;       // 2M x 2N wave grid
  const int lh = lane >> 5;

  // ---- ls-duty (n_blk == 0 blocks only): loss_s for rows rowA..rowA+127 ----
  if (n_blk == 0) {
    const signed char* A = (const signed char*)(ws + WS_A);
    const int* Tb = (const int*)(ws + WS_TS);
    const float* cnt = (const float*)(ws + WS_CNT);
    const float* ssq = (const float*)(ws + WS_SSQ);
    for (int rr = 0; rr < 32; ++rr) {
      const int row = rowA + wid * 32 + rr;
      const int c = ssec[row];
      const int* T = Tb + c * DD;
      union { int2 v; signed char b[8]; } u;
      u.v = *(const int2*)(A + (size_t)row * DD + lane * 8);
      i32x4 t0 = *(const i32x4*)(T + lane * 8);
      i32x4 t1 = *(const i32x4*)(T + lane * 8 + 4);
      int s = (int)u.b[0] * t0[0] + (int)u.b[1] * t0[1] +
              (int)u.b[2] * t0[2] + (int)u.b[3] * t0[3] +
              (int)u.b[4] * t1[0] + (int)u.b[5] * t1[1] +
              (int)u.b[6] * t1[2] + (int)u.b[7] * t1[3];
#pragma unroll
      for (int off = 32; off >= 1; off >>= 1) s += __shfl_xor(s, off, 64);
      if (lane == 0)
        out[row] = (cnt[c] * sqs[row] + ssq[c] - (float)s * (1.0f / 512.0f)) *
                   INV_DNT;
    }
  }

  // ---- staging: A 2 chunks, B 4 chunks per thread (16B each) ----
  const char* aSrc[2];
  const char* bSrc[4];
  int aDst[2], bDst[4];
#pragma unroll
  for (int ih = 0; ih < 2; ++ih) {
    const int o = ih * 4096 + tid * 16;
    const int row_p = o >> 6;
    const int bl = (o & 63) ^ (((row_p >> 1) & 3) << 4);
    aDst[ih] = ih * 4096 + wid * 1024;
    aSrc[ih] = ws + WS_A + (size_t)(rowA + row_p) * DD + bl;
  }
#pragma unroll
  for (int ih = 0; ih < 4; ++ih) {
    const int o = ih * 4096 + tid * 16;
    const int row_p = o >> 6;
    const int bl = (o & 63) ^ (((row_p >> 1) & 3) << 4);
    bDst[ih] = 8192 + ih * 4096 + wid * 1024;
    bSrc[ih] = ws + WS_B + (size_t)(rowB + row_p) * DD + bl;
  }

#define STAGE(T, BUF)                                             \
  {                                                               \
    gload16(aSrc[0] + (size_t)(T) * 64, &lds[BUF][aDst[0]]);      \
    gload16(aSrc[1] + (size_t)(T) * 64, &lds[BUF][aDst[1]]);      \
    gload16(bSrc[0] + (size_t)(T) * 64, &lds[BUF][bDst[0]]);      \
    gload16(bSrc[1] + (size_t)(T) * 64, &lds[BUF][bDst[1]]);      \
    gload16(bSrc[2] + (size_t)(T) * 64, &lds[BUF][bDst[2]]);      \
    gload16(bSrc[3] + (size_t)(T) * 64, &lds[BUF][bDst[3]]);      \
  }

  // ---- fragment read offsets (phys = logical ^ (((row>>1)&3)<<4)) ----
  int aOff[2][2], bOff[4][2];
#pragma unroll
  for (int kk = 0; kk < 2; ++kk) {
    const int l = kk * 32 + lh * 16;
#pragma unroll
    for (int mi = 0; mi < 2; ++mi) {
      const int ra = wr * 64 + mi * 32 + (lane & 31);
      aOff[mi][kk] = ra * 64 + (l ^ (((ra >> 1) & 3) << 4));
    }
#pragma unroll
    for (int ni = 0; ni < 4; ++ni) {
      const int rb = wc * 128 + ni * 32 + (lane & 31);
      bOff[ni][kk] = 8192 + rb * 64 + (l ^ (((rb >> 1) & 3) << 4));
    }
  }

  i32x16 acc[2][4];
#pragma unroll
  for (int mi = 0; mi < 2; ++mi)
#pragma unroll
    for (int ni = 0; ni < 4; ++ni)
#pragma unroll
      for (int j = 0; j < 16; ++j) acc[mi][ni][j] = 0;

  // ---- prologue ----
  STAGE(0, 0)
  STAGE(1, 1)
  asm volatile("s_waitcnt vmcnt(6)" ::: "memory");
  __builtin_amdgcn_sched_barrier(0);
  __builtin_amdgcn_s_barrier();

#pragma unroll
  for (int t = 0; t < 8; ++t) {
    const int cur = t % 3;
    if (t + 2 < 8) STAGE(t + 2, (t + 2) % 3)

    i32x4 a[2][2], b[4][2];
#pragma unroll
    for (int kk = 0; kk < 2; ++kk) {
#pragma unroll
      for (int mi = 0; mi < 2; ++mi)
        a[mi][kk] = *(const i32x4*)&lds[cur][aOff[mi][kk]];
#pragma unroll
      for (int ni = 0; ni < 4; ++ni)
        b[ni][kk] = *(const i32x4*)&lds[cur][bOff[ni][kk]];
    }
#pragma unroll
    for (int kk = 0; kk < 2; ++kk)
#pragma unroll
      for (int mi = 0; mi < 2; ++mi)
#pragma unroll
        for (int ni = 0; ni < 4; ++ni)
          acc[mi][ni] = __builtin_amdgcn_mfma_i32_32x32x32_i8(
              a[mi][kk], b[ni][kk], acc[mi][ni], 0, 0, 0);

    __builtin_amdgcn_sched_barrier(0);
    if (t + 2 < 8) {
      asm volatile("s_waitcnt vmcnt(6)" ::: "memory");   // tile t+1 landed
    } else if (t == 6) {
      asm volatile("s_waitcnt vmcnt(0)" ::: "memory");   // tile 7 landed
    }
    __builtin_amdgcn_sched_barrier(0);
    if (t < 7) __builtin_amdgcn_s_barrier();
  }
#undef STAGE

  // ---- epilogue: hinge detection only ----
  const int colc = lane & 31;
  float sqc[4];
#pragma unroll
  for (int ni = 0; ni < 4; ++ni)
    sqc[ni] = sqt[rowB + wc * 128 + ni * 32 + colc];

  float smin = sqs[rowA + wr * 64 + lane];       // wave-min of its 64 rows
#pragma unroll
  for (int off = 32; off >= 1; off >>= 1)
    smin = fminf(smin, __shfl_xor(smin, off, 64));

  int thr[4];
#pragma unroll
  for (int ni = 0; ni < 4; ++ni)
    thr[ni] = (int)((smin + sqc[ni] - 129.0f) * 512.0f);

  int mx[4] = {(int)0x80000000, (int)0x80000000,
               (int)0x80000000, (int)0x80000000};
#pragma unroll
  for (int mi = 0; mi < 2; ++mi)
#pragma unroll
    for (int ni = 0; ni < 4; ++ni)
#pragma unroll
      for (int j = 0; j < 16; ++j) mx[ni] = max(mx[ni], acc[mi][ni][j]);

  const bool fire = (mx[0] > thr[0]) || (mx[1] > thr[1]) ||
                    (mx[2] > thr[2]) || (mx[3] > thr[3]);
  if (__any(fire)) {                              // cold path (~never)
#pragma unroll
    for (int mi = 0; mi < 2; ++mi) {
#pragma unroll
      for (int j = 0; j < 16; ++j) {
        const int rowin = (j & 3) + 8 * (j >> 2) + 4 * lh;
        const int grow = rowA + wr * 64 + mi * 32 + rowin;
        const float sqr = sqs[grow];
        const int sc = ssec[grow];
#pragma unroll
        for (int ni = 0; ni < 4; ++ni) {
          const int gcol = rowB + wc * 128 + ni * 32 + colc;
          const float d2r =
              sqr + sqc[ni] - 2.f * (float)acc[mi][ni][j] * INV_S2;
          if (d2r < 128.f) {
            if (sc != tsec[gcol]) {                 // hinge contribution
              const float d = sqrtf(fmaxf(d2r, 0.f) * (1.f / (float)DD));
              const float hh = 0.5f - d;
              atomicAdd(&out[NS + grow], hh * hh * INV_NT);
            } else if (d2r < 0.f) {                 // clamp fix for loss_s
              atomicAdd(&out[grow], -d2r * INV_DNT);
            }
          }
        }
      }
    }
  }
}

extern "C" void kernel_launch(void* const* d_in, const int* in_sizes, int n_in,
                              void* d_out, int out_size, void* d_ws, size_t ws_size,
                              hipStream_t stream) {
  const float* src = (const float*)d_in[0];
  const float* tgt = (const float*)d_in[1];
  const int* ssec = (const int*)d_in[2];
  const int* tsec = (const int*)d_in[3];
  float* out = (float*)d_out;
  char* ws = (char*)d_ws;

  prep_kernel<<<1024, 256, 0, stream>>>(src, tgt, ws);
  tsumq_kernel<<<128, 512, 0, stream>>>(tsec, ws, out);
  gram_kernel<<<2048, 256, 0, stream>>>(ws, ssec, tsec, out);
}

// Round 15
// 78.448 us; speedup vs baseline: 1.2680x; 1.0454x over previous
//
#include <hip/hip_runtime.h>
#include <stdint.h>
#include <stddef.h>

#define NS 8192
#define NT 8192
#define DD 512
#define NSEC 6
#define QS 32.0f                                 // quant scale: q = rint(32*x)
#define INV_S2 (1.0f / (QS * QS))                // 1/1024
#define INV_DNT (1.0f / ((float)DD * (float)NT))
#define INV_NT  (1.0f / (float)NT)

typedef __attribute__((ext_vector_type(4))) int i32x4;
typedef __attribute__((ext_vector_type(16))) int i32x16;

// ---- workspace layout (bytes) ----
#define WS_A    ((size_t)0)                  // NS*DD i8
#define WS_B    (WS_A + (size_t)NS * DD)     // NT*DD i8
#define WS_SQS  (WS_B + (size_t)NT * DD)     // NS f32 raw row sumsq (exact fp32)
#define WS_SQT  (WS_SQS + (size_t)NS * 4)    // NT f32
#define WS_TS   (WS_SQT + (size_t)NT * 4)    // NSEC*DD i32 per-section q col-sums
#define WS_CNT  (WS_TS + (size_t)NSEC * DD * 4)  // NSEC f32
#define WS_SSQ  (WS_CNT + NSEC * 4)              // NSEC f32
#define WS_ZEND (WS_SSQ + NSEC * 4)

__device__ __forceinline__ void gload16(const void* g, void* l) {
  __builtin_amdgcn_global_load_lds(
      (const __attribute__((address_space(1))) unsigned int*)g,
      (__attribute__((address_space(3))) unsigned int*)l, 16, 0, 0);
}

// ============================================================================
// prep: fp32 -> i8 RTN quantization (scale 32) + exact fp32 row sum-of-squares.
// Block 0 zeroes the TS/CNT/SSQ accumulator region (replaces hipMemsetAsync).
// ============================================================================
__global__ __launch_bounds__(256) void prep_kernel(
    const float* __restrict__ src, const float* __restrict__ tgt,
    char* __restrict__ ws) {
  const int tid = threadIdx.x, wid = tid >> 6, lane = tid & 63;
  char* Ai8 = ws + WS_A;
  char* Bi8 = ws + WS_B;
  float* sqs = (float*)(ws + WS_SQS);
  float* sqt = (float*)(ws + WS_SQT);

  if (blockIdx.x == 0) {                     // zero TS/CNT/SSQ (3084 dwords)
    int* Z = (int*)(ws + WS_TS);
    for (int i = tid; i < (int)((WS_ZEND - WS_TS) >> 2); i += 256) Z[i] = 0;
  }

#pragma unroll
  for (int it = 0; it < 4; ++it) {
    const int row = blockIdx.x * 4 + wid + it * 4096;   // 0..16383
    const bool isT = row >= NS;
    const int r = isT ? row - NS : row;
    const float* in = (isT ? tgt : src) + (size_t)r * DD;
    const float4* rp = (const float4*)in;
    float4 v0 = rp[lane * 2], v1 = rp[lane * 2 + 1];
    float x[8] = {v0.x, v0.y, v0.z, v0.w, v1.x, v1.y, v1.z, v1.w};
    float ss = 0.f;
    int q[8];
#pragma unroll
    for (int j = 0; j < 8; ++j) {
      ss += x[j] * x[j];
      int qi = __float2int_rn(x[j] * QS);           // RTN, unbiased
      q[j] = min(127, max(-127, qi));
    }
    const int lo = (q[0] & 255) | ((q[1] & 255) << 8) |
                   ((q[2] & 255) << 16) | ((q[3] & 255) << 24);
    const int hi = (q[4] & 255) | ((q[5] & 255) << 8) |
                   ((q[6] & 255) << 16) | ((q[7] & 255) << 24);
    *(int2*)((isT ? Bi8 : Ai8) + (size_t)r * DD + lane * 8) = make_int2(lo, hi);
#pragma unroll
    for (int off = 32; off >= 1; off >>= 1) ss += __shfl_xor(ss, off, 64);
    if (lane == 0) (isT ? sqt : sqs)[r] = ss;
  }
}

// ============================================================================
// tsumq: per-section INTEGER column sums T[6][512] of the quantized targets,
// plus per-section cnt / sum(sqt).  128 blocks x 512 thr, 64 rows/block
// (the proven fast shape).  Also zeroes the loss_c half of out.
// ============================================================================
__global__ __launch_bounds__(512) void tsumq_kernel(
    const int* __restrict__ tsec, char* __restrict__ ws,
    float* __restrict__ out) {
  const int gid = blockIdx.x * 512 + threadIdx.x;
  if (gid < NS) out[NS + gid] = 0.f;            // loss_c accumulator base

  const int d = threadIdx.x;
  const int r0 = blockIdx.x * 64;
  const signed char* B = (const signed char*)(ws + WS_B);
  int a[NSEC] = {0, 0, 0, 0, 0, 0};
#pragma unroll 4
  for (int r = 0; r < 64; ++r) {
    const int sec = tsec[r0 + r];
    const int v = (int)B[(size_t)(r0 + r) * DD + d];
#pragma unroll
    for (int c = 0; c < NSEC; ++c) a[c] += (sec == c) ? v : 0;
  }
  int* T = (int*)(ws + WS_TS);
#pragma unroll
  for (int c = 0; c < NSEC; ++c) atomicAdd(&T[c * DD + d], a[c]);

  if (threadIdx.x < 64) {                       // cnt / ssq via wave 0
    const float* sqt = (const float*)(ws + WS_SQT);
    const int r = r0 + threadIdx.x;
    const int sec = tsec[r];
    const float qv = sqt[r];
    float cn[NSEC], sq[NSEC];
#pragma unroll
    for (int c = 0; c < NSEC; ++c) {
      cn[c] = (sec == c) ? 1.f : 0.f;
      sq[c] = (sec == c) ? qv : 0.f;
    }
#pragma unroll
    for (int c = 0; c < NSEC; ++c) {
#pragma unroll
      for (int off = 32; off >= 1; off >>= 1) {
        cn[c] += __shfl_xor(cn[c], off, 64);
        sq[c] += __shfl_xor(sq[c], off, 64);
      }
    }
    if (threadIdx.x == 0) {
      float* cnt = (float*)(ws + WS_CNT);
      float* ssq = (float*)(ws + WS_SSQ);
#pragma unroll
      for (int c = 0; c < NSEC; ++c) {
        atomicAdd(&cnt[c], cn[c]);
        atomicAdd(&ssq[c], sq[c]);
      }
    }
  }
}

// ============================================================================
// gram (i8): block 128x256, BK=64, 4 waves (2M x 2N), per-wave 64x128 =
// 2x4 frags of mfma_i32_32x32x32_i8.  3-buffer LDS pipeline, counted
// vmcnt(6).  Epilogue = hinge DETECTION only; cold path recomputes exactly.
// ls-duty: EVERY block computes loss_s for exactly 4 rows (wave wid ->
// row lin*4+wid; 2048 x 4 = 8192, bijective) -- evenly distributed, ~0.15 us
// per block (r14's 64-straggler-block concentration cost ~5 us).
// ============================================================================
__global__ __launch_bounds__(256, 2) void gram_kernel(
    const char* __restrict__ ws, const int* __restrict__ ssec,
    const int* __restrict__ tsec, float* __restrict__ out) {
  __shared__ __align__(16) char lds[3][24576];   // [buf][A 8KB | B 16KB]

  const float* sqs = (const float*)(ws + WS_SQS);
  const float* sqt = (const float*)(ws + WS_SQT);

  const int lin = blockIdx.x;                  // 2048 = 64(m) x 32(n)
  const int xcd = lin & 7, ii = lin >> 3;
  const int m_blk = xcd * 8 + (ii & 7);
  const int n_blk = ii >> 3;
  const int rowA = m_blk * 128, rowB = n_blk * 256;

  const int tid = threadIdx.x, wid = tid >> 6, lane = tid & 63;
  const int wr = wid >> 1, wc = wid & 1;       // 2M x 2N wave grid
  const int lh = lane >> 5;

  // ---- ls-duty: this block's 4 rows (wave wid -> row lin*4+wid) ----
  {
    const int row = lin * 4 + wid;             // 0..8191, bijective
    const int c = ssec[row];
    const signed char* A = (const signed char*)(ws + WS_A);
    const int* T = (const int*)(ws + WS_TS) + c * DD;
    union { int2 v; signed char b[8]; } u;
    u.v = *(const int2*)(A + (size_t)row * DD + lane * 8);
    i32x4 t0 = *(const i32x4*)(T + lane * 8);
    i32x4 t1 = *(const i32x4*)(T + lane * 8 + 4);
    int s = (int)u.b[0] * t0[0] + (int)u.b[1] * t0[1] +
            (int)u.b[2] * t0[2] + (int)u.b[3] * t0[3] +
            (int)u.b[4] * t1[0] + (int)u.b[5] * t1[1] +
            (int)u.b[6] * t1[2] + (int)u.b[7] * t1[3];
#pragma unroll
    for (int off = 32; off >= 1; off >>= 1) s += __shfl_xor(s, off, 64);
    if (lane == 0) {
      const float* cnt = (const float*)(ws + WS_CNT);
      const float* ssq = (const float*)(ws + WS_SSQ);
      out[row] = (cnt[c] * sqs[row] + ssq[c] - (float)s * (1.0f / 512.0f)) *
                 INV_DNT;
    }
  }

  // ---- staging: A 2 chunks, B 4 chunks per thread (16B each) ----
  const char* aSrc[2];
  const char* bSrc[4];
  int aDst[2], bDst[4];
#pragma unroll
  for (int ih = 0; ih < 2; ++ih) {
    const int o = ih * 4096 + tid * 16;
    const int row_p = o >> 6;
    const int bl = (o & 63) ^ (((row_p >> 1) & 3) << 4);
    aDst[ih] = ih * 4096 + wid * 1024;
    aSrc[ih] = ws + WS_A + (size_t)(rowA + row_p) * DD + bl;
  }
#pragma unroll
  for (int ih = 0; ih < 4; ++ih) {
    const int o = ih * 4096 + tid * 16;
    const int row_p = o >> 6;
    const int bl = (o & 63) ^ (((row_p >> 1) & 3) << 4);
    bDst[ih] = 8192 + ih * 4096 + wid * 1024;
    bSrc[ih] = ws + WS_B + (size_t)(rowB + row_p) * DD + bl;
  }

#define STAGE(T, BUF)                                             \
  {                                                               \
    gload16(aSrc[0] + (size_t)(T) * 64, &lds[BUF][aDst[0]]);      \
    gload16(aSrc[1] + (size_t)(T) * 64, &lds[BUF][aDst[1]]);      \
    gload16(bSrc[0] + (size_t)(T) * 64, &lds[BUF][bDst[0]]);      \
    gload16(bSrc[1] + (size_t)(T) * 64, &lds[BUF][bDst[1]]);      \
    gload16(bSrc[2] + (size_t)(T) * 64, &lds[BUF][bDst[2]]);      \
    gload16(bSrc[3] + (size_t)(T) * 64, &lds[BUF][bDst[3]]);      \
  }

  // ---- fragment read offsets (phys = logical ^ (((row>>1)&3)<<4)) ----
  int aOff[2][2], bOff[4][2];
#pragma unroll
  for (int kk = 0; kk < 2; ++kk) {
    const int l = kk * 32 + lh * 16;
#pragma unroll
    for (int mi = 0; mi < 2; ++mi) {
      const int ra = wr * 64 + mi * 32 + (lane & 31);
      aOff[mi][kk] = ra * 64 + (l ^ (((ra >> 1) & 3) << 4));
    }
#pragma unroll
    for (int ni = 0; ni < 4; ++ni) {
      const int rb = wc * 128 + ni * 32 + (lane & 31);
      bOff[ni][kk] = 8192 + rb * 64 + (l ^ (((rb >> 1) & 3) << 4));
    }
  }

  i32x16 acc[2][4];
#pragma unroll
  for (int mi = 0; mi < 2; ++mi)
#pragma unroll
    for (int ni = 0; ni < 4; ++ni)
#pragma unroll
      for (int j = 0; j < 16; ++j) acc[mi][ni][j] = 0;

  // ---- prologue ----
  STAGE(0, 0)
  STAGE(1, 1)
  asm volatile("s_waitcnt vmcnt(6)" ::: "memory");
  __builtin_amdgcn_sched_barrier(0);
  __builtin_amdgcn_s_barrier();

#pragma unroll
  for (int t = 0; t < 8; ++t) {
    const int cur = t % 3;
    if (t + 2 < 8) STAGE(t + 2, (t + 2) % 3)

    i32x4 a[2][2], b[4][2];
#pragma unroll
    for (int kk = 0; kk < 2; ++kk) {
#pragma unroll
      for (int mi = 0; mi < 2; ++mi)
        a[mi][kk] = *(const i32x4*)&lds[cur][aOff[mi][kk]];
#pragma unroll
      for (int ni = 0; ni < 4; ++ni)
        b[ni][kk] = *(const i32x4*)&lds[cur][bOff[ni][kk]];
    }
#pragma unroll
    for (int kk = 0; kk < 2; ++kk)
#pragma unroll
      for (int mi = 0; mi < 2; ++mi)
#pragma unroll
        for (int ni = 0; ni < 4; ++ni)
          acc[mi][ni] = __builtin_amdgcn_mfma_i32_32x32x32_i8(
              a[mi][kk], b[ni][kk], acc[mi][ni], 0, 0, 0);

    __builtin_amdgcn_sched_barrier(0);
    if (t + 2 < 8) {
      asm volatile("s_waitcnt vmcnt(6)" ::: "memory");   // tile t+1 landed
    } else if (t == 6) {
      asm volatile("s_waitcnt vmcnt(0)" ::: "memory");   // tile 7 landed
    }
    __builtin_amdgcn_sched_barrier(0);
    if (t < 7) __builtin_amdgcn_s_barrier();
  }
#undef STAGE

  // ---- epilogue: hinge detection only ----
  const int colc = lane & 31;
  float sqc[4];
#pragma unroll
  for (int ni = 0; ni < 4; ++ni)
    sqc[ni] = sqt[rowB + wc * 128 + ni * 32 + colc];

  float smin = sqs[rowA + wr * 64 + lane];       // wave-min of its 64 rows
#pragma unroll
  for (int off = 32; off >= 1; off >>= 1)
    smin = fminf(smin, __shfl_xor(smin, off, 64));

  int thr[4];
#pragma unroll
  for (int ni = 0; ni < 4; ++ni)
    thr[ni] = (int)((smin + sqc[ni] - 129.0f) * 512.0f);

  int mx[4] = {(int)0x80000000, (int)0x80000000,
               (int)0x80000000, (int)0x80000000};
#pragma unroll
  for (int mi = 0; mi < 2; ++mi)
#pragma unroll
    for (int ni = 0; ni < 4; ++ni)
#pragma unroll
      for (int j = 0; j < 16; ++j) mx[ni] = max(mx[ni], acc[mi][ni][j]);

  const bool fire = (mx[0] > thr[0]) || (mx[1] > thr[1]) ||
                    (mx[2] > thr[2]) || (mx[3] > thr[3]);
  if (__any(fire)) {                              // cold path (~never)
#pragma unroll
    for (int mi = 0; mi < 2; ++mi) {
#pragma unroll
      for (int j = 0; j < 16; ++j) {
        const int rowin = (j & 3) + 8 * (j >> 2) + 4 * lh;
        const int grow = rowA + wr * 64 + mi * 32 + rowin;
        const float sqr = sqs[grow];
        const int sc = ssec[grow];
#pragma unroll
        for (int ni = 0; ni < 4; ++ni) {
          const int gcol = rowB + wc * 128 + ni * 32 + colc;
          const float d2r =
              sqr + sqc[ni] - 2.f * (float)acc[mi][ni][j] * INV_S2;
          if (d2r < 128.f) {
            if (sc != tsec[gcol]) {                 // hinge contribution
              const float d = sqrtf(fmaxf(d2r, 0.f) * (1.f / (float)DD));
              const float hh = 0.5f - d;
              atomicAdd(&out[NS + grow], hh * hh * INV_NT);
            } else if (d2r < 0.f) {                 // clamp fix for loss_s
              atomicAdd(&out[grow], -d2r * INV_DNT);
            }
          }
        }
      }
    }
  }
}

extern "C" void kernel_launch(void* const* d_in, const int* in_sizes, int n_in,
                              void* d_out, int out_size, void* d_ws, size_t ws_size,
                              hipStream_t stream) {
  const float* src = (const float*)d_in[0];
  const float* tgt = (const float*)d_in[1];
  const int* ssec = (const int*)d_in[2];
  const int* tsec = (const int*)d_in[3];
  float* out = (float*)d_out;
  char* ws = (char*)d_ws;

  prep_kernel<<<1024, 256, 0, stream>>>(src, tgt, ws);
  tsumq_kernel<<<128, 512, 0, stream>>>(tsec, ws, out);
  gram_kernel<<<2048, 256, 0, stream>>>(ws, ssec, tsec, out);
}